// Round 4
// baseline (72.966 us; speedup 1.0000x reference)
//
#include <hip/hip_runtime.h>

#define NN 512
#define NWD 128
#define NSLICES 96                      // B*P*Q
#define NROWS (NSLICES * NN)            // 49152
#define BLOCKS_PER_SLICE 8
#define ROWS_PER_BLOCK (NN / BLOCKS_PER_SLICE)   // 64
#define NBLOCKS (NSLICES * BLOCKS_PER_SLICE)     // 768
#define ALPHA 0.2f

__device__ __forceinline__ float lrelu(float x) {
    return x > 0.f ? x : ALPHA * x;
}

// One kernel, slice-local. 8 blocks per (b,p,q) slice; each block:
//   Phase A: wa1 = W@a1, wa2 = W@a2 (coalesced wave-per-row-pair) -> LDS
//   Phase B: s1,s2 for ALL 512 slice rows -> LDS (st_feat slice is L2-shared
//            across the slice's 8 blocks via XCD-chunked blockIdx remap)
//   Phase C: stream 64 demand rows -> out with fused softmax.
//            rowmax is lrelu(s1_i + max_j s2_j): slice max M computed once.
__global__ __launch_bounds__(256) void fused_kernel(const float* __restrict__ demand,
                                                    const float* __restrict__ st,
                                                    const float* __restrict__ W,
                                                    const float* __restrict__ a,
                                                    float* __restrict__ out) {
    __shared__ float wa1[NWD];
    __shared__ float wa2[NWD];
    __shared__ float s1All[NN];
    __shared__ float s2All[NN];
    __shared__ float wmax[4];

    const int t = threadIdx.x;
    const int wid = t >> 6;
    const int lane = t & 63;
    const int l5 = lane & 31;       // position within half-wave
    const int half = lane >> 5;     // 0: even row of pair, 1: odd row

    // Bijective XCD-chunked remap: the 8 blocks of one slice share an XCD's L2.
    // (NBLOCKS == 768 == 96*8, physical round-robin p%8 -> XCD assumed; if the
    //  mapping differs it only affects locality, not correctness.)
    const int p = blockIdx.x;
    const int b = (p & 7) * (NBLOCKS / 8) + (p >> 3);
    const int slice = b >> 3;
    const int rowblk = (b & 7) * ROWS_PER_BLOCK;

    const float* stS = st + (long)slice * NN * NWD;

    // ---- Phase A: wa1/wa2, coalesced. Wave w covers W rows [32w, 32w+32). ----
    {
        const float4 a1v = *reinterpret_cast<const float4*>(a + l5 * 4);
        const float4 a2v = *reinterpret_cast<const float4*>(a + NWD + l5 * 4);
        #pragma unroll
        for (int i = 0; i < 16; ++i) {
            const int k = wid * 32 + i * 2;   // row pair (k, k+1)
            // lanes 0-31 -> row k cols 0..127, lanes 32-63 -> row k+1 (contiguous 1 KB)
            const float4 wv = *reinterpret_cast<const float4*>(W + (long)k * NWD + lane * 4);
            float p1 = wv.x * a1v.x + wv.y * a1v.y + wv.z * a1v.z + wv.w * a1v.w;
            float p2 = wv.x * a2v.x + wv.y * a2v.y + wv.z * a2v.z + wv.w * a2v.w;
            #pragma unroll
            for (int off = 16; off > 0; off >>= 1) {
                p1 += __shfl_xor(p1, off);
                p2 += __shfl_xor(p2, off);
            }
            if (l5 == 0) { wa1[k + half] = p1; wa2[k + half] = p2; }
        }
    }
    __syncthreads();

    // ---- Phase B: s1,s2 for all 512 slice rows. Wave w covers rows [128w, 128w+128). ----
    {
        const float4 w1v = *reinterpret_cast<const float4*>(&wa1[l5 * 4]);
        const float4 w2v = *reinterpret_cast<const float4*>(&wa2[l5 * 4]);
        #pragma unroll 4
        for (int i = 0; i < 64; ++i) {
            const int r = wid * 128 + i * 2;   // row pair (r, r+1)
            const float4 f = *reinterpret_cast<const float4*>(stS + (long)r * NWD + lane * 4);
            float p1 = f.x * w1v.x + f.y * w1v.y + f.z * w1v.z + f.w * w1v.w;
            float p2 = f.x * w2v.x + f.y * w2v.y + f.z * w2v.z + f.w * w2v.w;
            #pragma unroll
            for (int off = 16; off > 0; off >>= 1) {
                p1 += __shfl_xor(p1, off);
                p2 += __shfl_xor(p2, off);
            }
            if (l5 == 0) { s1All[r + half] = p1; s2All[r + half] = p2; }
        }
    }
    __syncthreads();

    // ---- Slice max M = max_j s2[j] ----
    {
        float ml = fmaxf(s2All[t], s2All[t + 256]);
        #pragma unroll
        for (int off = 32; off > 0; off >>= 1) ml = fmaxf(ml, __shfl_xor(ml, off));
        if (lane == 0) wmax[wid] = ml;
    }
    __syncthreads();
    const float M = fmaxf(fmaxf(wmax[0], wmax[1]), fmaxf(wmax[2], wmax[3]));

    // ---- Phase C: stream our 64 rows. Wave handles 16 rows; s2 fragment in regs. ----
    const int c0 = lane * 4;
    const int c1 = 256 + lane * 4;
    const float4 sa = *reinterpret_cast<const float4*>(&s2All[c0]);
    const float4 sb = *reinterpret_cast<const float4*>(&s2All[c1]);

    for (int i = 0; i < 16; ++i) {
        const int row = rowblk + wid * 16 + i;
        const long g = (long)slice * NN + row;
        const float s1i = s1All[row];
        const float m = lrelu(s1i + M);   // exact rowmax (lrelu monotone)

        float pv[8];
        pv[0] = __expf(lrelu(s1i + sa.x) - m);
        pv[1] = __expf(lrelu(s1i + sa.y) - m);
        pv[2] = __expf(lrelu(s1i + sa.z) - m);
        pv[3] = __expf(lrelu(s1i + sa.w) - m);
        pv[4] = __expf(lrelu(s1i + sb.x) - m);
        pv[5] = __expf(lrelu(s1i + sb.y) - m);
        pv[6] = __expf(lrelu(s1i + sb.z) - m);
        pv[7] = __expf(lrelu(s1i + sb.w) - m);

        float sum = 0.f;
        #pragma unroll
        for (int k = 0; k < 8; ++k) sum += pv[k];
        #pragma unroll
        for (int off = 32; off > 0; off >>= 1) sum += __shfl_xor(sum, off);
        const float inv = 1.f / sum;

        const float* drow = demand + g * NN;
        const float4 d0 = *reinterpret_cast<const float4*>(drow + c0);
        const float4 d1 = *reinterpret_cast<const float4*>(drow + c1);

        float4 o0, o1;
        o0.x = lrelu(d0.x * pv[0] * inv); o0.y = lrelu(d0.y * pv[1] * inv);
        o0.z = lrelu(d0.z * pv[2] * inv); o0.w = lrelu(d0.w * pv[3] * inv);
        o1.x = lrelu(d1.x * pv[4] * inv); o1.y = lrelu(d1.y * pv[5] * inv);
        o1.z = lrelu(d1.z * pv[6] * inv); o1.w = lrelu(d1.w * pv[7] * inv);

        float* orow = out + g * NN;
        *reinterpret_cast<float4*>(orow + c0) = o0;
        *reinterpret_cast<float4*>(orow + c1) = o1;
    }
}

extern "C" void kernel_launch(void* const* d_in, const int* in_sizes, int n_in,
                              void* d_out, int out_size, void* d_ws, size_t ws_size,
                              hipStream_t stream) {
    const float* demand  = (const float*)d_in[0];
    const float* st_feat = (const float*)d_in[1];
    const float* W       = (const float*)d_in[2];
    const float* a       = (const float*)d_in[3];
    float* out = (float*)d_out;

    fused_kernel<<<NBLOCKS, 256, 0, stream>>>(demand, st_feat, W, a, out);
}

// Round 5
// 48.619 us; speedup vs baseline: 1.5008x; 1.5008x over previous
//
#include <hip/hip_runtime.h>

#define NN 512
#define NWD 128
#define NSLICES 96                      // B*P*Q
#define NROWS (NSLICES * NN)            // 49152
#define ALPHA 0.2f

__device__ __forceinline__ float lrelu(float x) {
    return x > 0.f ? x : ALPHA * x;
}

// Kernel 1: fused wa + s, 768 blocks x 64 rows each, NO redundant row work.
//   Phase A (per-block redundant, coalesced): wa1 = W@a1, wa2 = W@a2 -> LDS.
//     Wave w covers W rows [32w,32w+32) as 16 row-pairs; a wave's 64 lanes
//     read one contiguous 1 KB line pair; 5-round half-wave butterfly.
//   Phase B: s1,s2 for this block's OWN 64 rows. Each wave: 8 iters x 2 rows,
//     float4 (16 B/lane), 5-round half-wave butterfly.
__global__ __launch_bounds__(256) void s_fused_kernel(const float* __restrict__ st,
                                                      const float* __restrict__ W,
                                                      const float* __restrict__ a,
                                                      float* __restrict__ s1,
                                                      float* __restrict__ s2) {
    __shared__ float wa1[NWD];
    __shared__ float wa2[NWD];

    const int t = threadIdx.x;
    const int wid = t >> 6;
    const int lane = t & 63;
    const int l5 = lane & 31;       // position within half-wave
    const int half = lane >> 5;     // 0: even row of pair, 1: odd row

    // ---- Phase A: coalesced wa ----
    {
        const float4 a1v = *reinterpret_cast<const float4*>(a + l5 * 4);
        const float4 a2v = *reinterpret_cast<const float4*>(a + NWD + l5 * 4);
        #pragma unroll
        for (int i = 0; i < 16; ++i) {
            const int k = wid * 32 + i * 2;   // W row pair (k, k+1)
            const float4 wv = *reinterpret_cast<const float4*>(W + (long)k * NWD + lane * 4);
            float p1 = wv.x * a1v.x + wv.y * a1v.y + wv.z * a1v.z + wv.w * a1v.w;
            float p2 = wv.x * a2v.x + wv.y * a2v.y + wv.z * a2v.z + wv.w * a2v.w;
            #pragma unroll
            for (int off = 16; off > 0; off >>= 1) {
                p1 += __shfl_xor(p1, off);
                p2 += __shfl_xor(p2, off);
            }
            if (l5 == 0) { wa1[k + half] = p1; wa2[k + half] = p2; }
        }
    }
    __syncthreads();

    // ---- Phase B: s for own 64 rows ----
    const float4 w1v = *reinterpret_cast<const float4*>(&wa1[l5 * 4]);
    const float4 w2v = *reinterpret_cast<const float4*>(&wa2[l5 * 4]);
    const long blockbase = (long)blockIdx.x * 64;

    #pragma unroll
    for (int i = 0; i < 8; ++i) {
        const long rowpair = blockbase + (long)wid * 16 + i * 2;
        const float4 f = *reinterpret_cast<const float4*>(st + rowpair * NWD + lane * 4);
        float p1 = f.x * w1v.x + f.y * w1v.y + f.z * w1v.z + f.w * w1v.w;
        float p2 = f.x * w2v.x + f.y * w2v.y + f.z * w2v.z + f.w * w2v.w;
        #pragma unroll
        for (int off = 16; off > 0; off >>= 1) {
            p1 += __shfl_xor(p1, off);
            p2 += __shfl_xor(p2, off);
        }
        if (l5 == 0) {
            const long g = rowpair + half;
            s1[g] = p1;
            s2[g] = p2;
        }
    }
}

// Kernel 2: per output row: e[j] = lrelu(s1[i]+s2[j]); softmax over j;
// out[j] = lrelu(demand[j] * att[j]).  One wave per row, 8 cols/lane (2x float4).
__global__ __launch_bounds__(256) void main_kernel(const float* __restrict__ demand,
                                                   const float* __restrict__ s1,
                                                   const float* __restrict__ s2,
                                                   float* __restrict__ out) {
    int wid = threadIdx.x >> 6;
    int lane = threadIdx.x & 63;
    long g = (long)blockIdx.x * 4 + wid;     // global row, 0 .. NROWS-1
    long slice = g >> 9;                     // (b,p,q) index
    float s1i = s1[g];
    const float* s2s = s2 + slice * NN;

    const int c0 = lane * 4;
    const int c1 = 256 + lane * 4;
    const float4 sa = *reinterpret_cast<const float4*>(s2s + c0);
    const float4 sb = *reinterpret_cast<const float4*>(s2s + c1);

    float e[8];
    e[0] = lrelu(s1i + sa.x); e[1] = lrelu(s1i + sa.y);
    e[2] = lrelu(s1i + sa.z); e[3] = lrelu(s1i + sa.w);
    e[4] = lrelu(s1i + sb.x); e[5] = lrelu(s1i + sb.y);
    e[6] = lrelu(s1i + sb.z); e[7] = lrelu(s1i + sb.w);

    float m = e[0];
    #pragma unroll
    for (int k = 1; k < 8; ++k) m = fmaxf(m, e[k]);
    #pragma unroll
    for (int off = 32; off > 0; off >>= 1) m = fmaxf(m, __shfl_xor(m, off));

    float p[8];
    float sum = 0.f;
    #pragma unroll
    for (int k = 0; k < 8; ++k) { p[k] = __expf(e[k] - m); sum += p[k]; }
    #pragma unroll
    for (int off = 32; off > 0; off >>= 1) sum += __shfl_xor(sum, off);
    const float inv = 1.f / sum;

    const float* drow = demand + g * NN;
    const float4 d0 = *reinterpret_cast<const float4*>(drow + c0);
    const float4 d1 = *reinterpret_cast<const float4*>(drow + c1);

    float4 o0, o1;
    o0.x = lrelu(d0.x * p[0] * inv); o0.y = lrelu(d0.y * p[1] * inv);
    o0.z = lrelu(d0.z * p[2] * inv); o0.w = lrelu(d0.w * p[3] * inv);
    o1.x = lrelu(d1.x * p[4] * inv); o1.y = lrelu(d1.y * p[5] * inv);
    o1.z = lrelu(d1.z * p[6] * inv); o1.w = lrelu(d1.w * p[7] * inv);

    float* orow = out + g * NN;
    *reinterpret_cast<float4*>(orow + c0) = o0;
    *reinterpret_cast<float4*>(orow + c1) = o1;
}

extern "C" void kernel_launch(void* const* d_in, const int* in_sizes, int n_in,
                              void* d_out, int out_size, void* d_ws, size_t ws_size,
                              hipStream_t stream) {
    const float* demand  = (const float*)d_in[0];
    const float* st_feat = (const float*)d_in[1];
    const float* W       = (const float*)d_in[2];
    const float* a       = (const float*)d_in[3];
    float* out = (float*)d_out;

    float* s1 = (float*)d_ws;                  // NROWS floats
    float* s2 = s1 + NROWS;                    // NROWS floats

    s_fused_kernel<<<NROWS / 64, 256, 0, stream>>>(st_feat, W, a, s1, s2);
    main_kernel<<<NROWS / 4, 256, 0, stream>>>(demand, s1, s2, out);
}